// Round 1
// baseline (267.120 us; speedup 1.0000x reference)
//
#include <hip/hip_runtime.h>

#define N_NODES 100000
#define N_EDGES 800000
#define IN_SIZE 128
#define OUT_SIZE 64

// ---------------------------------------------------------------------------
// Kernel 1: H0 = data @ W + b   (fp32, no MFMA on CDNA4 for fp32)
// block = 256 (4 waves); each wave computes 4 rows x 64 cols.
// W (128x64 = 32KB) staged in LDS once per block; row loads forced scalar
// via readfirstlane so one ds_read of W[k][c] feeds 4 FMAs.
// grid = N_NODES/16 = 6250 (exact).
// ---------------------------------------------------------------------------
__global__ __launch_bounds__(256) void gemm_bias_kernel(
    const float* __restrict__ data, const float* __restrict__ W,
    const float* __restrict__ b, float* __restrict__ H)
{
    __shared__ float Wlds[IN_SIZE * OUT_SIZE];
    const int tid = threadIdx.x;
    {
        const float4* Wg = (const float4*)W;
        float4* Wl = (float4*)Wlds;
        #pragma unroll
        for (int i = 0; i < 8; ++i)
            Wl[tid + 256 * i] = Wg[tid + 256 * i];
    }
    __syncthreads();

    const int lane = tid & 63;
    const int wave = tid >> 6;
    const int row0 = __builtin_amdgcn_readfirstlane((int)(blockIdx.x * 16 + wave * 4));

    const float bb = b[lane];
    float acc0 = bb, acc1 = bb, acc2 = bb, acc3 = bb;

    const float* r0 = data + (size_t)row0 * IN_SIZE;
    const float* r1 = r0 + IN_SIZE;
    const float* r2 = r1 + IN_SIZE;
    const float* r3 = r2 + IN_SIZE;

    #pragma unroll 8
    for (int k = 0; k < IN_SIZE; ++k) {
        const float wv = Wlds[k * OUT_SIZE + lane];
        acc0 += r0[k] * wv;
        acc1 += r1[k] * wv;
        acc2 += r2[k] * wv;
        acc3 += r3[k] * wv;
    }

    float* o = H + (size_t)row0 * OUT_SIZE + lane;
    o[0 * OUT_SIZE] = acc0;
    o[1 * OUT_SIZE] = acc1;
    o[2 * OUT_SIZE] = acc2;
    o[3 * OUT_SIZE] = acc3;
}

// ---------------------------------------------------------------------------
// Kernel 2: CSR row pointers from sorted tgt via per-node lower_bound.
// rowptr[t] = first edge index with tgt[e] >= t, for t in [0, N_NODES].
// ---------------------------------------------------------------------------
__global__ __launch_bounds__(256) void rowptr_kernel(
    const int* __restrict__ tgt, int* __restrict__ rowptr)
{
    const int t = blockIdx.x * blockDim.x + threadIdx.x;
    if (t > N_NODES) return;
    int lo = 0, hi = N_EDGES;
    while (lo < hi) {
        const int mid = (lo + hi) >> 1;
        if (tgt[mid] < t) lo = mid + 1; else hi = mid;
    }
    rowptr[t] = lo;
}

// ---------------------------------------------------------------------------
// Kernel 3/4: one propagation round.
// out[t] = (in[t] + sum_{e: tgt_e = t} in[src_e]) / (deg(t)+1); 0 if deg==0.
// One wave per node, lane = feature channel (64 channels -> 256B gathers).
// 2-edge unrolled independent accumulators for ILP.
// grid = N_NODES/4 = 25000 (exact), block = 256.
// ---------------------------------------------------------------------------
template <bool RELU>
__global__ __launch_bounds__(256) void prop_kernel(
    const float* __restrict__ in, float* __restrict__ out,
    const int* __restrict__ rowptr, const int* __restrict__ src)
{
    const int lane = threadIdx.x & 63;
    const int node = blockIdx.x * 4 + (threadIdx.x >> 6);

    const int start = rowptr[node];
    const int end   = rowptr[node + 1];
    const int deg   = end - start;

    float val;
    if (deg == 0) {
        val = 0.0f;
    } else {
        float acc  = in[(size_t)node * OUT_SIZE + lane];
        float acc2 = 0.0f;
        int e = start;
        for (; e + 1 < end; e += 2) {
            const int s0 = src[e];
            const int s1 = src[e + 1];
            acc  += in[(size_t)s0 * OUT_SIZE + lane];
            acc2 += in[(size_t)s1 * OUT_SIZE + lane];
        }
        if (e < end) {
            const int s0 = src[e];
            acc += in[(size_t)s0 * OUT_SIZE + lane];
        }
        val = (acc + acc2) / (float)(deg + 1);
    }
    if (RELU) val = fmaxf(val, 0.0f);
    out[(size_t)node * OUT_SIZE + lane] = val;
}

// ---------------------------------------------------------------------------
// Launch
// ---------------------------------------------------------------------------
extern "C" void kernel_launch(void* const* d_in, const int* in_sizes, int n_in,
                              void* d_out, int out_size, void* d_ws, size_t ws_size,
                              hipStream_t stream)
{
    const float* data = (const float*)d_in[0];
    const float* W    = (const float*)d_in[1];
    const float* b    = (const float*)d_in[2];
    const int*   src  = (const int*)d_in[3];
    const int*   tgt  = (const int*)d_in[4];
    float*       out  = (float*)d_out;

    // workspace layout: H0 (25.6MB) | H1 (25.6MB) | rowptr (400KB)
    float* H0     = (float*)d_ws;
    float* H1     = H0 + (size_t)N_NODES * OUT_SIZE;
    int*   rowptr = (int*)(H1 + (size_t)N_NODES * OUT_SIZE);

    gemm_bias_kernel<<<N_NODES / 16, 256, 0, stream>>>(data, W, b, H0);
    rowptr_kernel<<<(N_NODES + 1 + 255) / 256, 256, 0, stream>>>(tgt, rowptr);
    prop_kernel<false><<<N_NODES / 4, 256, 0, stream>>>(H0, H1, rowptr, src);
    prop_kernel<true ><<<N_NODES / 4, 256, 0, stream>>>(H1, out, rowptr, src);
}

// Round 2
// 218.033 us; speedup vs baseline: 1.2251x; 1.2251x over previous
//
#include <hip/hip_runtime.h>

#define N_NODES 100000
#define N_EDGES 800000
#define IN_SIZE 128
#define OUT_SIZE 64

// ---------------------------------------------------------------------------
// Kernel 1: H0 = data @ W + b   (fp32 vector ALU; no fp32 MFMA on CDNA4)
// v2: W column held in VGPRs (128 regs/lane, lane = output col), rows stream
// through SGPRs via readfirstlane-uniform pointers (s_load). No LDS in loop,
// so lgkmcnt is scalar-only and the body is pure v_fmac_f32.
// block = 256 (4 waves) x 8 rows/wave = 32 rows/block; grid = 3125 (exact).
// ---------------------------------------------------------------------------
__global__ __launch_bounds__(256) void gemm_bias_kernel(
    const float* __restrict__ data, const float* __restrict__ W,
    const float* __restrict__ b, float* __restrict__ H)
{
    const int tid  = threadIdx.x;
    const int lane = tid & 63;
    const int wave = tid >> 6;

    // each lane owns output column `lane`: W[:, lane] into VGPRs
    float w[IN_SIZE];
    #pragma unroll
    for (int k = 0; k < IN_SIZE; ++k)
        w[k] = W[k * OUT_SIZE + lane];

    const int row0 = __builtin_amdgcn_readfirstlane(
        (int)(blockIdx.x * 32 + wave * 8));

    const float bb = b[lane];
    float acc[8];
    #pragma unroll
    for (int i = 0; i < 8; ++i) acc[i] = bb;

    const float* __restrict__ r = data + (size_t)row0 * IN_SIZE;

    #pragma unroll
    for (int k = 0; k < IN_SIZE; ++k) {
        const float wv = w[k];
        #pragma unroll
        for (int i = 0; i < 8; ++i)
            acc[i] += r[(size_t)i * IN_SIZE + k] * wv;
    }

    float* o = H + (size_t)row0 * OUT_SIZE + lane;
    #pragma unroll
    for (int i = 0; i < 8; ++i)
        o[(size_t)i * OUT_SIZE] = acc[i];
}

// ---------------------------------------------------------------------------
// Kernel 2: CSR row pointers from sorted tgt via per-node lower_bound.
// ---------------------------------------------------------------------------
__global__ __launch_bounds__(256) void rowptr_kernel(
    const int* __restrict__ tgt, int* __restrict__ rowptr)
{
    const int t = blockIdx.x * blockDim.x + threadIdx.x;
    if (t > N_NODES) return;
    int lo = 0, hi = N_EDGES;
    while (lo < hi) {
        const int mid = (lo + hi) >> 1;
        if (tgt[mid] < t) lo = mid + 1; else hi = mid;
    }
    rowptr[t] = lo;
}

// ---------------------------------------------------------------------------
// Kernel 3/4: one propagation round.
// out[t] = (in[t] + sum_{e: tgt_e=t} in[src_e]) / (deg(t)+1); 0 if deg==0.
// v2: one wave per node, 4 edge-subgroups (g = lane>>4) x 16 lanes, each lane
// loads float4 (16B) -> 4 edges (8 with unroll) in flight per wave.
// Cross-subgroup reduction via shfl_xor(16), shfl_xor(32).
// grid = N_NODES/4 = 25000 (exact), block = 256.
// ---------------------------------------------------------------------------
__device__ __forceinline__ void f4_add(float4& a, const float4 b) {
    a.x += b.x; a.y += b.y; a.z += b.z; a.w += b.w;
}

template <bool RELU>
__global__ __launch_bounds__(256) void prop_kernel(
    const float4* __restrict__ in4, float4* __restrict__ out4,
    const int* __restrict__ rowptr, const int* __restrict__ src)
{
    const int tid  = threadIdx.x;
    const int lane = tid & 63;
    const int wave = tid >> 6;
    const int g    = lane >> 4;   // edge subgroup 0..3
    const int c4   = lane & 15;   // float4 channel group (channels 4*c4..+3)
    const int node = blockIdx.x * 4 + wave;

    const int start = rowptr[node];
    const int end   = rowptr[node + 1];
    const int deg   = end - start;

    // own contribution issued early to overlap gather latency
    const float4 own = in4[(size_t)node * 16 + c4];

    float4 acc  = make_float4(0.f, 0.f, 0.f, 0.f);
    float4 acc2 = make_float4(0.f, 0.f, 0.f, 0.f);

    int e = start + g;
    for (; e + 4 < end; e += 8) {
        const int s0 = src[e];
        const int s1 = src[e + 4];
        const float4 v0 = in4[(size_t)s0 * 16 + c4];
        const float4 v1 = in4[(size_t)s1 * 16 + c4];
        f4_add(acc, v0);
        f4_add(acc2, v1);
    }
    if (e < end) {
        const int s0 = src[e];
        f4_add(acc, in4[(size_t)s0 * 16 + c4]);
    }
    f4_add(acc, acc2);

    // reduce across the 4 edge subgroups (lanes differing in bits 4,5)
    acc.x += __shfl_xor(acc.x, 16, 64);
    acc.y += __shfl_xor(acc.y, 16, 64);
    acc.z += __shfl_xor(acc.z, 16, 64);
    acc.w += __shfl_xor(acc.w, 16, 64);
    acc.x += __shfl_xor(acc.x, 32, 64);
    acc.y += __shfl_xor(acc.y, 32, 64);
    acc.z += __shfl_xor(acc.z, 32, 64);
    acc.w += __shfl_xor(acc.w, 32, 64);

    if (g == 0) {
        float4 val;
        if (deg == 0) {
            val = make_float4(0.f, 0.f, 0.f, 0.f);
        } else {
            const float inv = 1.0f / (float)(deg + 1);
            val.x = (own.x + acc.x) * inv;
            val.y = (own.y + acc.y) * inv;
            val.z = (own.z + acc.z) * inv;
            val.w = (own.w + acc.w) * inv;
            if (RELU) {
                val.x = fmaxf(val.x, 0.f);
                val.y = fmaxf(val.y, 0.f);
                val.z = fmaxf(val.z, 0.f);
                val.w = fmaxf(val.w, 0.f);
            }
        }
        out4[(size_t)node * 16 + c4] = val;
    }
}

// ---------------------------------------------------------------------------
// Launch
// ---------------------------------------------------------------------------
extern "C" void kernel_launch(void* const* d_in, const int* in_sizes, int n_in,
                              void* d_out, int out_size, void* d_ws, size_t ws_size,
                              hipStream_t stream)
{
    const float* data = (const float*)d_in[0];
    const float* W    = (const float*)d_in[1];
    const float* b    = (const float*)d_in[2];
    const int*   src  = (const int*)d_in[3];
    const int*   tgt  = (const int*)d_in[4];

    // workspace layout: H0 (25.6MB) | H1 (25.6MB) | rowptr (400KB)
    float* H0     = (float*)d_ws;
    float* H1     = H0 + (size_t)N_NODES * OUT_SIZE;
    int*   rowptr = (int*)(H1 + (size_t)N_NODES * OUT_SIZE);

    gemm_bias_kernel<<<N_NODES / 32, 256, 0, stream>>>(data, W, b, H0);
    rowptr_kernel<<<(N_NODES + 1 + 255) / 256, 256, 0, stream>>>(tgt, rowptr);
    prop_kernel<false><<<N_NODES / 4, 256, 0, stream>>>(
        (const float4*)H0, (float4*)H1, rowptr, src);
    prop_kernel<true ><<<N_NODES / 4, 256, 0, stream>>>(
        (const float4*)H1, (float4*)d_out, rowptr, src);
}

// Round 3
// 191.098 us; speedup vs baseline: 1.3978x; 1.1409x over previous
//
#include <hip/hip_runtime.h>

#define N_NODES 100000
#define N_EDGES 800000
#define IN_SIZE 128
#define OUT_SIZE 64

// ---------------------------------------------------------------------------
// Kernel 1: H0 = data @ W + b  (fp32 vector ALU; no fp32 MFMA on CDNA4)
// v3: classic LDS-tiled GEMM. Block tile = 64 rows x 64 cols, K staged in two
// 64-wide halves (A-half 64x68 padded = 17.4KB, W-half 64x64 = 16KB -> 33.8KB
// LDS, 4 blocks/CU). Thread = 4 rows x 4 cols; per 4-k chunk: 8 ds_read_b128
// (~96 cyc/wave) vs 64 v_fmac (128 cyc/wave) -> VALU-bound.
// Pad ASTR=68: ty-groups land 16 banks apart -> 2-way aliasing (free).
// Compute floor: 8.19e8 FMA / 32.8 FMA/cyc-chip = ~10.4 us; mem ~13 us.
// ---------------------------------------------------------------------------
#define GR 64            // rows per block tile
#define KH 64            // k half staged at a time
#define ASTR (KH + 4)    // 68-float row stride in LDS

__global__ __launch_bounds__(256) void gemm_bias_kernel(
    const float* __restrict__ data, const float* __restrict__ W,
    const float* __restrict__ b, float* __restrict__ H)
{
    __shared__ __align__(16) float Alds[GR * ASTR];     // 17408 B
    __shared__ __align__(16) float Wlds[KH * OUT_SIZE]; // 16384 B

    const int tid = threadIdx.x;
    const int tx  = tid & 15;   // col group: cols 4*tx..+3
    const int ty  = tid >> 4;   // row group: rows 4*ty..+3
    const int r0  = blockIdx.x * GR;

    float acc[4][4];
    {
        const float4 bb = *(const float4*)(b + tx * 4);
        #pragma unroll
        for (int i = 0; i < 4; ++i) {
            acc[i][0] = bb.x; acc[i][1] = bb.y; acc[i][2] = bb.z; acc[i][3] = bb.w;
        }
    }

    // staging mapping: 16 lanes per row -> 256B contiguous global reads
    const int srow = tid >> 4;        // 0..15
    const int skc  = (tid & 15) * 4;  // k offset within half

    #pragma unroll
    for (int h = 0; h < 2; ++h) {
        __syncthreads();  // protect previous half's reads (no-op cost at h=0)
        #pragma unroll
        for (int p = 0; p < 4; ++p) {
            const int row = p * 16 + srow;
            int grow = r0 + row;
            grow = grow < N_NODES ? grow : N_NODES - 1;  // clamp; stores guarded
            const float4 v = *(const float4*)(data + (size_t)grow * IN_SIZE + h * KH + skc);
            *(float4*)(Alds + row * ASTR + skc) = v;
        }
        {
            const float4* Wg = (const float4*)(W + h * KH * OUT_SIZE);
            float4* Wl = (float4*)Wlds;
            #pragma unroll
            for (int p = 0; p < 4; ++p)
                Wl[p * 256 + tid] = Wg[p * 256 + tid];
        }
        __syncthreads();

        const float* Arow = Alds + (ty * 4) * ASTR;
        const float* Wcol = Wlds + tx * 4;
        #pragma unroll 4
        for (int k = 0; k < KH; k += 4) {
            float4 av4[4], wv4[4];
            #pragma unroll
            for (int i = 0; i < 4; ++i)
                av4[i] = *(const float4*)(Arow + i * ASTR + k);
            #pragma unroll
            for (int kk = 0; kk < 4; ++kk)
                wv4[kk] = *(const float4*)(Wcol + (k + kk) * OUT_SIZE);
            const float* av = (const float*)av4;  // av[i*4+kk] = A[row i][k+kk]
            const float* wv = (const float*)wv4;  // wv[kk*4+j] = W[k+kk][col j]
            #pragma unroll
            for (int i = 0; i < 4; ++i) {
                #pragma unroll
                for (int kk = 0; kk < 4; ++kk) {
                    const float a = av[i * 4 + kk];
                    #pragma unroll
                    for (int j = 0; j < 4; ++j)
                        acc[i][j] += a * wv[kk * 4 + j];
                }
            }
        }
    }

    #pragma unroll
    for (int i = 0; i < 4; ++i) {
        const int row = r0 + ty * 4 + i;
        if (row < N_NODES) {
            float4 o;
            o.x = acc[i][0]; o.y = acc[i][1]; o.z = acc[i][2]; o.w = acc[i][3];
            *(float4*)(H + (size_t)row * OUT_SIZE + tx * 4) = o;
        }
    }
}

// ---------------------------------------------------------------------------
// Kernel 2: CSR row pointers from sorted tgt via per-node lower_bound.
// ---------------------------------------------------------------------------
__global__ __launch_bounds__(256) void rowptr_kernel(
    const int* __restrict__ tgt, int* __restrict__ rowptr)
{
    const int t = blockIdx.x * blockDim.x + threadIdx.x;
    if (t > N_NODES) return;
    int lo = 0, hi = N_EDGES;
    while (lo < hi) {
        const int mid = (lo + hi) >> 1;
        if (tgt[mid] < t) lo = mid + 1; else hi = mid;
    }
    rowptr[t] = lo;
}

// ---------------------------------------------------------------------------
// Kernel 3/4: one propagation round.
// out[t] = (in[t] + sum_{e: tgt_e=t} in[src_e]) / (deg(t)+1); 0 if deg==0.
// v3: one 16-lane subgroup per node (16 nodes/block). Lanes cooperatively
// load up to 16 src indices at once, broadcast via shfl, and issue gathers
// in masked chunks of 4 -> up to 16 independent 256B gathers in flight per
// node (64/wave) instead of 8/wave. No cross-subgroup reduction needed.
// Masked-out slots gather node 0 (valid memory, L1-hot) x 0.0 weight.
// ---------------------------------------------------------------------------
__device__ __forceinline__ void f4_add(float4& a, const float4 b) {
    a.x += b.x; a.y += b.y; a.z += b.z; a.w += b.w;
}
__device__ __forceinline__ void f4_fma(float4& a, const float4 v, const float m) {
    a.x = fmaf(v.x, m, a.x);
    a.y = fmaf(v.y, m, a.y);
    a.z = fmaf(v.z, m, a.z);
    a.w = fmaf(v.w, m, a.w);
}

template <bool RELU>
__global__ __launch_bounds__(256) void prop_kernel(
    const float4* __restrict__ in4, float4* __restrict__ out4,
    const int* __restrict__ rowptr, const int* __restrict__ src)
{
    const int tid   = threadIdx.x;
    const int lane  = tid & 63;
    const int c4    = lane & 15;        // float4 channel chunk
    const int lbase = lane & 48;        // subgroup base lane within wave
    const int node  = blockIdx.x * 16 + (tid >> 4);

    const int start = rowptr[node];
    const int end   = rowptr[node + 1];
    const int deg   = end - start;

    const float4 own = in4[(size_t)node * 16 + c4];

    float4 acc0 = make_float4(0.f, 0.f, 0.f, 0.f);
    float4 acc1 = make_float4(0.f, 0.f, 0.f, 0.f);
    float4 acc2 = make_float4(0.f, 0.f, 0.f, 0.f);
    float4 acc3 = make_float4(0.f, 0.f, 0.f, 0.f);

    for (int base = start; base < end; base += 16) {
        const int li = base + c4;
        const int sv = (li < end) ? src[li] : 0;  // 16 consecutive src idx
        int cm = end - base;
        cm = cm < 16 ? cm : 16;

        #pragma unroll
        for (int j0 = 0; j0 < 16; j0 += 4) {
            if (j0 < cm) {
                const int s0 = __shfl(sv, lbase + j0 + 0, 64);
                const int s1 = __shfl(sv, lbase + j0 + 1, 64);
                const int s2 = __shfl(sv, lbase + j0 + 2, 64);
                const int s3 = __shfl(sv, lbase + j0 + 3, 64);
                const float m1 = (j0 + 1 < cm) ? 1.f : 0.f;
                const float m2 = (j0 + 2 < cm) ? 1.f : 0.f;
                const float m3 = (j0 + 3 < cm) ? 1.f : 0.f;
                const float4 v0 = in4[(size_t)s0 * 16 + c4];
                const float4 v1 = in4[(size_t)s1 * 16 + c4];
                const float4 v2 = in4[(size_t)s2 * 16 + c4];
                const float4 v3 = in4[(size_t)s3 * 16 + c4];
                f4_add(acc0, v0);           // j0+0 < cm guaranteed here
                f4_fma(acc1, v1, m1);
                f4_fma(acc2, v2, m2);
                f4_fma(acc3, v3, m3);
            }
        }
    }

    f4_add(acc0, acc1);
    f4_add(acc2, acc3);
    f4_add(acc0, acc2);

    float4 val;
    if (deg == 0) {
        val = make_float4(0.f, 0.f, 0.f, 0.f);
    } else {
        const float inv = 1.0f / (float)(deg + 1);
        val.x = (own.x + acc0.x) * inv;
        val.y = (own.y + acc0.y) * inv;
        val.z = (own.z + acc0.z) * inv;
        val.w = (own.w + acc0.w) * inv;
        if (RELU) {
            val.x = fmaxf(val.x, 0.f);
            val.y = fmaxf(val.y, 0.f);
            val.z = fmaxf(val.z, 0.f);
            val.w = fmaxf(val.w, 0.f);
        }
    }
    out4[(size_t)node * 16 + c4] = val;
}

// ---------------------------------------------------------------------------
// Launch
// ---------------------------------------------------------------------------
extern "C" void kernel_launch(void* const* d_in, const int* in_sizes, int n_in,
                              void* d_out, int out_size, void* d_ws, size_t ws_size,
                              hipStream_t stream)
{
    const float* data = (const float*)d_in[0];
    const float* W    = (const float*)d_in[1];
    const float* b    = (const float*)d_in[2];
    const int*   src  = (const int*)d_in[3];
    const int*   tgt  = (const int*)d_in[4];

    // workspace layout: H0 (25.6MB) | H1 (25.6MB) | rowptr (400KB)
    float* H0     = (float*)d_ws;
    float* H1     = H0 + (size_t)N_NODES * OUT_SIZE;
    int*   rowptr = (int*)(H1 + (size_t)N_NODES * OUT_SIZE);

    gemm_bias_kernel<<<(N_NODES + GR - 1) / GR, 256, 0, stream>>>(data, W, b, H0);
    rowptr_kernel<<<(N_NODES + 1 + 255) / 256, 256, 0, stream>>>(tgt, rowptr);
    prop_kernel<false><<<N_NODES / 16, 256, 0, stream>>>(
        (const float4*)H0, (float4*)H1, rowptr, src);
    prop_kernel<true ><<<N_NODES / 16, 256, 0, stream>>>(
        (const float4*)H1, (float4*)d_out, rowptr, src);
}

// Round 4
// 152.159 us; speedup vs baseline: 1.7555x; 1.2559x over previous
//
#include <hip/hip_runtime.h>

#define N_NODES 100000
#define N_EDGES 800000
#define IN_SIZE 128
#define OUT_SIZE 64

#define GEMM_BLOCKS 512
#define RP_BLOCKS   128
#define N_TILES     (N_NODES / 16)   // 6250 exact

typedef __attribute__((ext_vector_type(8))) short short8;
typedef __attribute__((ext_vector_type(4))) float f32x4;

__device__ __forceinline__ unsigned short f2bf(float x) {
    unsigned u = __float_as_uint(x);
    u += 0x7FFFu + ((u >> 16) & 1u);          // round-to-nearest-even
    return (unsigned short)(u >> 16);
}
__device__ __forceinline__ unsigned pack2(float lo, float hi) {
    return (unsigned)f2bf(lo) | ((unsigned)f2bf(hi) << 16);
}
__device__ __forceinline__ float bflo(unsigned u) { return __uint_as_float(u << 16); }
__device__ __forceinline__ float bfhi(unsigned u) { return __uint_as_float(u & 0xFFFF0000u); }

// ---------------------------------------------------------------------------
// Kernel 1 (fused): H0 = bf16(data @ W + b)  via MFMA  +  CSR rowptr build.
// GEMM: persistent waves, each owns a 16-row tile per iteration.
//  - W frags (4 kc x 4 nt, B-layout B[k=quad*8+j][n=lane&15]) built once per
//    wave from global (32KB, L2-hot across 2048 waves).
//  - A frags: lane = row (lane&15), 2x float4 loads -> 8 bf16 (A[m][k=quad*8+j]).
//  - 16 mfma_f32_16x16x32_bf16 per tile; C/D: col=lane&15, row=quad*4+reg.
//  - Epilogue: +bias, bf16, transpose through wave-private LDS (stride 72
//    ushorts: quads land 2-way on banks = free) -> coalesced 16B row stores.
// Memory floor: 51.2MB read + 12.8MB write ~ 10us. No __syncthreads at all.
// rowptr: blocks >= GEMM_BLOCKS binary-search sorted tgt (grid-stride).
// ---------------------------------------------------------------------------
__global__ __launch_bounds__(256) void gemm_rowptr_kernel(
    const float* __restrict__ data, const float* __restrict__ W,
    const float* __restrict__ b, const int* __restrict__ tgt,
    unsigned short* __restrict__ H, int* __restrict__ rowptr)
{
    if (blockIdx.x >= GEMM_BLOCKS) {
        int t = (int)(blockIdx.x - GEMM_BLOCKS) * 256 + (int)threadIdx.x;
        for (; t <= N_NODES; t += RP_BLOCKS * 256) {
            int lo = 0, hi = N_EDGES;
            while (lo < hi) {
                const int mid = (lo + hi) >> 1;
                if (tgt[mid] < t) lo = mid + 1; else hi = mid;
            }
            rowptr[t] = lo;
        }
        return;
    }

    __shared__ unsigned short Clds[4][16 * 72];  // 9216 B; wave-private regions

    const int tid  = threadIdx.x;
    const int lane = tid & 63;
    const int wv   = tid >> 6;
    const int quad = lane >> 4;
    const int col  = lane & 15;

    union U8 { short8 v; unsigned short u[8]; };

    // B fragments from global W (fp32 -> bf16)
    short8 wb[4][4];
    #pragma unroll
    for (int kc = 0; kc < 4; ++kc) {
        #pragma unroll
        for (int nt = 0; nt < 4; ++nt) {
            U8 t;
            #pragma unroll
            for (int j = 0; j < 8; ++j) {
                const int k = kc * 32 + quad * 8 + j;
                t.u[j] = f2bf(W[k * OUT_SIZE + nt * 16 + col]);
            }
            wb[kc][nt] = t.v;
        }
    }
    float bcol[4];
    #pragma unroll
    for (int nt = 0; nt < 4; ++nt) bcol[nt] = b[nt * 16 + col];

    unsigned short* cl = Clds[wv];
    const int gw = blockIdx.x * 4 + wv;

    for (int tile = gw; tile < N_TILES; tile += GEMM_BLOCKS * 4) {
        const int r0 = tile * 16;
        const float* arow = data + (size_t)(r0 + col) * IN_SIZE + quad * 8;

        short8 af[4];
        #pragma unroll
        for (int kc = 0; kc < 4; ++kc) {
            const float4 x0 = *(const float4*)(arow + kc * 32);
            const float4 x1 = *(const float4*)(arow + kc * 32 + 4);
            U8 t;
            t.u[0] = f2bf(x0.x); t.u[1] = f2bf(x0.y);
            t.u[2] = f2bf(x0.z); t.u[3] = f2bf(x0.w);
            t.u[4] = f2bf(x1.x); t.u[5] = f2bf(x1.y);
            t.u[6] = f2bf(x1.z); t.u[7] = f2bf(x1.w);
            af[kc] = t.v;
        }

        f32x4 acc[4];
        #pragma unroll
        for (int nt = 0; nt < 4; ++nt) acc[nt] = (f32x4){0.f, 0.f, 0.f, 0.f};
        #pragma unroll
        for (int kc = 0; kc < 4; ++kc) {
            #pragma unroll
            for (int nt = 0; nt < 4; ++nt)
                acc[nt] = __builtin_amdgcn_mfma_f32_16x16x32_bf16(
                    af[kc], wb[kc][nt], acc[nt], 0, 0, 0);
        }

        // epilogue: bias + bf16 into wave-private LDS (C-layout scatter)
        #pragma unroll
        for (int nt = 0; nt < 4; ++nt) {
            #pragma unroll
            for (int r = 0; r < 4; ++r)
                cl[(quad * 4 + r) * 72 + nt * 16 + col] =
                    f2bf(acc[nt][r] + bcol[nt]);
        }
        // transpose readback -> coalesced row-major stores (same-wave LDS
        // ordering; compiler inserts lgkmcnt, no barrier needed)
        #pragma unroll
        for (int p = 0; p < 2; ++p) {
            const int row = p * 8 + (lane >> 3);
            const int seg = lane & 7;
            const uint4 vv = *(const uint4*)(cl + row * 72 + seg * 8);
            *(uint4*)(H + (size_t)(r0 + row) * OUT_SIZE + seg * 8) = vv;
        }
    }
}

// ---------------------------------------------------------------------------
// Kernel 2/3: one propagation round on bf16 rows (128 B/node).
// out[t] = (in[t] + sum_{e: tgt_e=t} in[src_e]) / (deg+1); 0 if deg==0.
// 8-lane subgroup per node, lane loads ushort8 (16B) -> one vmem instruction
// gathers 8 full edge-rows (one per subgroup). Edges batched 8 at a time via
// cooperative src load + shfl broadcast; masked fma for the tail.
// FINAL: fp32 + relu to d_out; else bf16 to H1.
// ---------------------------------------------------------------------------
__device__ __forceinline__ void acc_add(float* a, const uint4 v) {
    a[0] += bflo(v.x); a[1] += bfhi(v.x);
    a[2] += bflo(v.y); a[3] += bfhi(v.y);
    a[4] += bflo(v.z); a[5] += bfhi(v.z);
    a[6] += bflo(v.w); a[7] += bfhi(v.w);
}
__device__ __forceinline__ void acc_fma(float* a, const uint4 v, const float m) {
    a[0] = fmaf(bflo(v.x), m, a[0]); a[1] = fmaf(bfhi(v.x), m, a[1]);
    a[2] = fmaf(bflo(v.y), m, a[2]); a[3] = fmaf(bfhi(v.y), m, a[3]);
    a[4] = fmaf(bflo(v.z), m, a[4]); a[5] = fmaf(bfhi(v.z), m, a[5]);
    a[6] = fmaf(bflo(v.w), m, a[6]); a[7] = fmaf(bfhi(v.w), m, a[7]);
}

template <bool FINAL>
__global__ __launch_bounds__(256) void prop_kernel(
    const unsigned short* __restrict__ in, void* __restrict__ outp,
    const int* __restrict__ rowptr, const int* __restrict__ src)
{
    const int tid   = threadIdx.x;
    const int lane  = tid & 63;
    const int s     = lane & 7;     // 16B chunk within row
    const int lbase = lane & 56;    // subgroup base lane
    const int node  = blockIdx.x * 32 + (tid >> 3);

    const int start = rowptr[node];
    const int end   = rowptr[node + 1];
    const int deg   = end - start;

    const uint4* inq = (const uint4*)in;    // 8 chunks per row
    const uint4 ownq = inq[(size_t)node * 8 + s];

    float acc[8];
    #pragma unroll
    for (int k = 0; k < 8; ++k) acc[k] = 0.f;

    for (int base = start; base < end; base += 8) {
        const int li = base + s;
        const int sv = (li < end) ? src[li] : 0;
        int cm = end - base; cm = cm < 8 ? cm : 8;
        #pragma unroll
        for (int j0 = 0; j0 < 8; j0 += 4) {
            if (j0 < cm) {
                const int s0 = __shfl(sv, lbase + j0 + 0, 64);
                const int s1 = __shfl(sv, lbase + j0 + 1, 64);
                const int s2 = __shfl(sv, lbase + j0 + 2, 64);
                const int s3 = __shfl(sv, lbase + j0 + 3, 64);
                const float m1 = (j0 + 1 < cm) ? 1.f : 0.f;
                const float m2 = (j0 + 2 < cm) ? 1.f : 0.f;
                const float m3 = (j0 + 3 < cm) ? 1.f : 0.f;
                const uint4 v0 = inq[(size_t)s0 * 8 + s];
                const uint4 v1 = inq[(size_t)s1 * 8 + s];
                const uint4 v2 = inq[(size_t)s2 * 8 + s];
                const uint4 v3 = inq[(size_t)s3 * 8 + s];
                acc_add(acc, v0);            // j0 < cm guarantees edge j0 valid
                acc_fma(acc, v1, m1);
                acc_fma(acc, v2, m2);
                acc_fma(acc, v3, m3);
            }
        }
    }

    float o[8];
    if (deg == 0) {
        #pragma unroll
        for (int k = 0; k < 8; ++k) o[k] = 0.f;
    } else {
        const float inv = 1.0f / (float)(deg + 1);
        float own[8];
        acc_add(acc, ownq);  // add own row
        #pragma unroll
        for (int k = 0; k < 8; ++k) {
            o[k] = acc[k] * inv;
            if (FINAL) o[k] = fmaxf(o[k], 0.f);
        }
        (void)own;
    }

    if (FINAL) {
        float* out = (float*)outp;
        float4 lo, hi;
        lo.x = o[0]; lo.y = o[1]; lo.z = o[2]; lo.w = o[3];
        hi.x = o[4]; hi.y = o[5]; hi.z = o[6]; hi.w = o[7];
        *(float4*)(out + (size_t)node * OUT_SIZE + s * 8)     = lo;
        *(float4*)(out + (size_t)node * OUT_SIZE + s * 8 + 4) = hi;
    } else {
        uint4 pv;
        pv.x = pack2(o[0], o[1]);
        pv.y = pack2(o[2], o[3]);
        pv.z = pack2(o[4], o[5]);
        pv.w = pack2(o[6], o[7]);
        ((uint4*)outp)[(size_t)node * 8 + s] = pv;
    }
}

// ---------------------------------------------------------------------------
// Launch
// ---------------------------------------------------------------------------
extern "C" void kernel_launch(void* const* d_in, const int* in_sizes, int n_in,
                              void* d_out, int out_size, void* d_ws, size_t ws_size,
                              hipStream_t stream)
{
    const float* data = (const float*)d_in[0];
    const float* W    = (const float*)d_in[1];
    const float* b    = (const float*)d_in[2];
    const int*   src  = (const int*)d_in[3];
    const int*   tgt  = (const int*)d_in[4];

    // ws: H0 bf16 (12.8MB) | H1 bf16 (12.8MB) | rowptr (400KB)
    unsigned short* H0 = (unsigned short*)d_ws;
    unsigned short* H1 = H0 + (size_t)N_NODES * OUT_SIZE;
    int* rowptr        = (int*)(H1 + (size_t)N_NODES * OUT_SIZE);

    gemm_rowptr_kernel<<<GEMM_BLOCKS + RP_BLOCKS, 256, 0, stream>>>(
        data, W, b, tgt, H0, rowptr);
    prop_kernel<false><<<N_NODES / 32, 256, 0, stream>>>(H0, H1, rowptr, src);
    prop_kernel<true ><<<N_NODES / 32, 256, 0, stream>>>(H1, d_out, rowptr, src);
}